// Round 7
// baseline (297.963 us; speedup 1.0000x reference)
//
#include <hip/hip_runtime.h>
#include <hip/hip_bf16.h>

// InfoNCE: a[4096,512], p[4096,512], n[16384,512] f32 -> 4 f32 scalars.
// R11 = R10 with the fence builtin fixed (__hip_atomic_thread_fence -> __threadfence).
//  (1) R9 post-mortem: gemm0 hit LDS-read BW, not MFMA (each wave read the
//      full 128-col B tile: 8xb128 = 8KB/wave/tile -> ~1000cyc/CU/iter vs
//      310cyc MFMA). Retile waves 16x128 -> 32x64 (wr=w>>1, wc=w&1): A-regs
//      double to 64 VGPR (af[2][8]), B reads HALVE (4xb128). Same slot
//      formula -> bank pattern unchanged (measured 0 conflicts in R9).
//  (2) Dispatch-sum undershoots dur_us by ~100us across R4-R9 (5 serialized
//      dispatches). Fuse norm+gemm0+gemm1+finalize into ONE kernel with
//      manual grid barriers (threadfence -> atomicAdd -> spin -> threadfence).
//      Co-residency guaranteed: launch_bounds(512,4) caps VGPR at 128 ->
//      exactly 2 blocks/CU x 256 CU = 512 blocks; LDS 34KB/block.
//  Revert path if this round fails: R9 + the 32x64 retile.
// ws layout: a8(2MB) p8(2MB) n8(8MB) | S[4096] csA[8192] csP[8192] csN[8192]
//            lsum[1] pad[3] cnt[4]

#define D_DIM 512
#define B_ROWS 4096
#define P_ROWS 4096
#define N_ROWS 16384
#define INV_T 14.285714285714286f
#define EPS_L 1e-8f
#define CS_STRIDE 16
#define GRID 512

typedef unsigned char fp8_t;
typedef __attribute__((ext_vector_type(4))) float floatx4;   // MFMA C/D frag
typedef __attribute__((ext_vector_type(2))) long longx2;     // 16B = 2 MFMA operands
typedef unsigned int uint32;

#define BM 128
#define BN 128
#define BKB 64   // K-elements per B tile == bytes per row per tile (fp8)
#define NBUF 4

typedef const __attribute__((address_space(1))) unsigned int* as1_u32p;
typedef __attribute__((address_space(3))) unsigned int* as3_u32p;

__device__ __forceinline__ void load_lds16(const void* g, void* l) {
    // each lane writes 16B at (wave-uniform l) + lane*16
    __builtin_amdgcn_global_load_lds((as1_u32p)g, (as3_u32p)l, 16, 0, 0);
}

// device-wide barrier: all GRID blocks are co-resident by construction.
// __threadfence() = device-scope fence (release before arrive, acquire after).
__device__ __forceinline__ void grid_bar(uint32* cnt) {
    __syncthreads();
    if (threadIdx.x == 0) {
        __threadfence();
        atomicAdd(cnt, 1u);
        while (__hip_atomic_load(cnt, __ATOMIC_RELAXED, __HIP_MEMORY_SCOPE_AGENT) < GRID)
            __builtin_amdgcn_s_sleep(2);
        __threadfence();
    }
    __syncthreads();
}

// ---- gemm phase body: A in regs (32 rows/wave), B 4-ring LDS, 1 barrier/iter.
// Wave grid 4(M: wr) x 2(N: wc); per wave 32x64 output, 4 b128 B-reads/k-chunk.
// EPI==0: S[row] += sum_col exp(C*invT); EPI==1: lsum over -log(pe/(pe+S)+eps).
template <int EPI, int TN>
__device__ __forceinline__ void gemm_body(const fp8_t* __restrict__ A,
                                          const fp8_t* __restrict__ Bm,
                                          float* __restrict__ S,
                                          float* __restrict__ loss_sum,
                                          int m0, int nt0, int tid,
                                          fp8_t (*Bl)[BN * BKB], float* csh) {
    const int lane = tid & 63;
    const int w    = tid >> 6;      // 0..7
    const int wr   = w >> 1;        // 0..3: 32-row band
    const int wc   = w & 1;         // 0..1: 64-col half
    const int lr   = lane & 15;
    const int q    = lane >> 4;

    // A fragments: rows m0+wr*32+{lr,16+lr}, true bytes kt*64+q*16 (matches
    // B's granule mapping -> per-(q,half) true-k identical on both sides).
    longx2 af[2][8];
#pragma unroll
    for (int rt = 0; rt < 2; ++rt) {
        const fp8_t* arow = A + (size_t)(m0 + wr * 32 + rt * 16 + lr) * D_DIM + q * 16;
#pragma unroll
        for (int kt = 0; kt < 8; ++kt)
            af[rt][kt] = *reinterpret_cast<const longx2*>(arow + kt * 64);
    }

    // B staging (R7/R9's measured-zero-conflict scheme, stride 64):
    // LDS[r*64 + s*16] holds true granule s^((r>>1)&3) of row r.
    const int sr = lane >> 2;
    const int sg = (lane & 3) ^ ((lane >> 3) & 3);
    const fp8_t* bbase = Bm + (size_t)(nt0 * BN + w * 16 + sr) * D_DIM + sg * 16;
    const int goff = (q ^ ((lr >> 1) & 3)) << 4;

    auto stage = [&](int tt) {
        load_lds16(bbase + (size_t)(tt >> 3) * (size_t)(BN * D_DIM)
                         + (size_t)((tt & 7) * BKB),
                   &Bl[tt & 3][w * 16 * BKB]);
    };

    float vac[2][4];
    float Sv[2][4];
    float lsum = 0.f;
    if (EPI == 0) {
#pragma unroll
        for (int rt = 0; rt < 2; ++rt)
#pragma unroll
            for (int reg = 0; reg < 4; ++reg) vac[rt][reg] = 0.f;
    } else {
#pragma unroll
        for (int rt = 0; rt < 2; ++rt)
#pragma unroll
            for (int reg = 0; reg < 4; ++reg)
                Sv[rt][reg] = S[m0 + wr * 32 + rt * 16 + q * 4 + reg];
    }

    stage(0);
    stage(1);

    for (int j = 0; j < TN; ++j) {
        floatx4 acc[2][4];
#pragma unroll
        for (int rt = 0; rt < 2; ++rt)
#pragma unroll
            for (int ct = 0; ct < 4; ++ct) acc[rt][ct] = (floatx4){0.f, 0.f, 0.f, 0.f};

#pragma unroll
        for (int kt = 0; kt < 8; ++kt) {
            const int tt = j * 8 + kt;
            if (tt < TN * 8 - 2) {
                stage(tt + 2);   // ring dist 2, depth 4: writers never collide
                asm volatile("s_waitcnt vmcnt(2)" ::: "memory");  // tile tt landed
            } else if (tt == TN * 8 - 2) {
                asm volatile("s_waitcnt vmcnt(1)" ::: "memory");
            } else {
                asm volatile("s_waitcnt vmcnt(0)" ::: "memory");
            }
            __builtin_amdgcn_sched_barrier(0);
            __builtin_amdgcn_s_barrier();   // only barrier: tile tt resident
            __builtin_amdgcn_sched_barrier(0);

            const fp8_t* bl = &Bl[tt & 3][0];
            __builtin_amdgcn_s_setprio(1);
#pragma unroll
            for (int ct = 0; ct < 4; ++ct) {
                const int r = wc * 64 + ct * 16 + lr;
                longx2 bv = *reinterpret_cast<const longx2*>(&bl[r * BKB + goff]);
                acc[0][ct] = __builtin_amdgcn_mfma_f32_16x16x32_fp8_fp8(
                    af[0][kt].x, bv.x, acc[0][ct], 0, 0, 0);
                acc[1][ct] = __builtin_amdgcn_mfma_f32_16x16x32_fp8_fp8(
                    af[1][kt].x, bv.x, acc[1][ct], 0, 0, 0);
                acc[0][ct] = __builtin_amdgcn_mfma_f32_16x16x32_fp8_fp8(
                    af[0][kt].y, bv.y, acc[0][ct], 0, 0, 0);
                acc[1][ct] = __builtin_amdgcn_mfma_f32_16x16x32_fp8_fp8(
                    af[1][kt].y, bv.y, acc[1][ct], 0, 0, 0);
            }
            __builtin_amdgcn_s_setprio(0);
            __builtin_amdgcn_sched_barrier(0);
        }

        // per-n-tile epilogue, register-only (vmcnt counts stay exact).
        // C/D layout: col = lane&15, row = (lane>>4)*4 + reg
        if (EPI == 0) {
#pragma unroll
            for (int rt = 0; rt < 2; ++rt)
#pragma unroll
                for (int reg = 0; reg < 4; ++reg) {
                    float v = 0.f;
#pragma unroll
                    for (int ct = 0; ct < 4; ++ct) v += __expf(acc[rt][ct][reg] * INV_T);
                    vac[rt][reg] += v;
                }
        } else {
#pragma unroll
            for (int rt = 0; rt < 2; ++rt)
#pragma unroll
                for (int reg = 0; reg < 4; ++reg) {
                    float s = Sv[rt][reg];
#pragma unroll
                    for (int ct = 0; ct < 4; ++ct) {
                        float pe = __expf(acc[rt][ct][reg] * INV_T);
                        lsum -= __logf(pe / (pe + s) + EPS_L);
                    }
                }
        }
    }

    if (EPI == 0) {
#pragma unroll
        for (int rt = 0; rt < 2; ++rt)
#pragma unroll
            for (int reg = 0; reg < 4; ++reg) {
                float v = vac[rt][reg];
                v += __shfl_xor(v, 1);
                v += __shfl_xor(v, 2);
                v += __shfl_xor(v, 4);
                v += __shfl_xor(v, 8);
                if (lr == 0)
                    atomicAdd(&S[m0 + wr * 32 + rt * 16 + q * 4 + reg], v);
            }
    } else {
#pragma unroll
        for (int off = 1; off < 64; off <<= 1) lsum += __shfl_xor(lsum, off);
        __syncthreads();
        if (lane == 0) csh[w] = lsum;
        __syncthreads();
        if (tid == 0) {
            float s = 0.f;
#pragma unroll
            for (int i = 0; i < 8; ++i) s += csh[i];
            atomicAdd(loss_sum, s);
        }
    }
}

// ================= fully fused kernel: 512 blocks x 512 threads =================
__global__ __launch_bounds__(512, 4) void fused_all(
        const float* __restrict__ anc, const float* __restrict__ pos,
        const float* __restrict__ neg,
        fp8_t* __restrict__ a8, fp8_t* __restrict__ p8, fp8_t* __restrict__ n8,
        float* __restrict__ S, float* __restrict__ csA, float* __restrict__ csP,
        float* __restrict__ csN, float* __restrict__ lsum,
        uint32* __restrict__ cnt, float* __restrict__ out) {
    __shared__ fp8_t Bl[NBUF][BN * BKB];   // 32 KB gemm ring
    __shared__ float csh[D_DIM];           // 2 KB: colsum / lsum scratch
    __shared__ int lastf;

    const int b    = blockIdx.x;
    const int tid  = threadIdx.x;
    const int lane = tid & 63;
    const int w    = tid >> 6;

    // ---------------- phase 0: L2-normalize -> fp8, colsums ----------------
    {
        const float* in; fp8_t* outp; float* cs; int gw, nw, rows;
        if (b < 128)      { in = anc; outp = a8; cs = csA; gw = b * 8 + w;         nw = 1024; rows = B_ROWS; }
        else if (b < 256) { in = pos; outp = p8; cs = csP; gw = (b - 128) * 8 + w; nw = 1024; rows = P_ROWS; }
        else              { in = neg; outp = n8; cs = csN; gw = (b - 256) * 8 + w; nw = 2048; rows = N_ROWS; }

        float cs0[4] = {0.f, 0.f, 0.f, 0.f};
        float cs1[4] = {0.f, 0.f, 0.f, 0.f};

        for (int r = gw; r < rows; r += nw) {
            const float4* rp = reinterpret_cast<const float4*>(in + (size_t)r * D_DIM);
            float4 v0 = rp[lane];
            float4 v1 = rp[lane + 64];
            float ss = v0.x*v0.x + v0.y*v0.y + v0.z*v0.z + v0.w*v0.w
                     + v1.x*v1.x + v1.y*v1.y + v1.z*v1.z + v1.w*v1.w;
#pragma unroll
            for (int off = 1; off < 64; off <<= 1) ss += __shfl_xor(ss, off);
            float inv = 1.0f / fmaxf(sqrtf(ss), 1e-12f);
            float f0x = v0.x*inv, f0y = v0.y*inv, f0z = v0.z*inv, f0w = v0.w*inv;
            float f1x = v1.x*inv, f1y = v1.y*inv, f1z = v1.z*inv, f1w = v1.w*inv;
            cs0[0] += f0x; cs0[1] += f0y; cs0[2] += f0z; cs0[3] += f0w;
            cs1[0] += f1x; cs1[1] += f1y; cs1[2] += f1z; cs1[3] += f1w;
            int pk0 = __builtin_amdgcn_cvt_pk_fp8_f32(f0x, f0y, 0, 0);
            pk0     = __builtin_amdgcn_cvt_pk_fp8_f32(f0z, f0w, pk0, 1);
            int pk1 = __builtin_amdgcn_cvt_pk_fp8_f32(f1x, f1y, 0, 0);
            pk1     = __builtin_amdgcn_cvt_pk_fp8_f32(f1z, f1w, pk1, 1);
            uint32* op = reinterpret_cast<uint32*>(outp + (size_t)r * D_DIM);
            op[lane]      = (uint32)pk0;
            op[lane + 64] = (uint32)pk1;
        }

        csh[tid] = 0.f;
        __syncthreads();
#pragma unroll
        for (int j = 0; j < 4; ++j) {
            atomicAdd(&csh[lane * 4 + j], cs0[j]);
            atomicAdd(&csh[256 + lane * 4 + j], cs1[j]);
        }
        __syncthreads();
        atomicAdd(&cs[(size_t)tid * CS_STRIDE], csh[tid]);
    }

    grid_bar(&cnt[0]);   // publishes a8/p8/n8 + colsums

    // ---------------- phase 1: neg GEMM (S exp-sums) ----------------
    gemm_body<0, 8>(a8, n8, S, nullptr, (b >> 4) * BM, (b & 15) * 8, tid, Bl, csh);

    grid_bar(&cnt[1]);   // S complete

    // ---------------- phase 2: pos GEMM (loss) ----------------
    gemm_body<1, 2>(a8, p8, S, lsum, (b >> 4) * BM, (b & 15) * 2, tid, Bl, csh);

    // ---------------- arrive; last block finalizes ----------------
    __syncthreads();
    if (tid == 0) {
        __threadfence();
        uint32 p = atomicAdd(&cnt[2], 1u);
        lastf = (p == GRID - 1);
    }
    __syncthreads();
    if (lastf) {
        __threadfence();
        float av = csA[(size_t)tid * CS_STRIDE];
        float dp = av * csP[(size_t)tid * CS_STRIDE];
        float dn = av * csN[(size_t)tid * CS_STRIDE];
#pragma unroll
        for (int off = 1; off < 64; off <<= 1) {
            dp += __shfl_xor(dp, off);
            dn += __shfl_xor(dn, off);
        }
        __syncthreads();
        float* red = csh;
        if (lane == 0) { red[w] = dp; red[8 + w] = dn; }
        __syncthreads();
        if (tid == 0) {
            float sdp = 0.f, sdn = 0.f;
#pragma unroll
            for (int i = 0; i < 8; ++i) { sdp += red[i]; sdn += red[8 + i]; }
            float mean_pos = sdp * INV_T / ((float)B_ROWS * (float)P_ROWS);
            float mean_neg = sdn * INV_T / ((float)B_ROWS * (float)N_ROWS);
            out[0] = lsum[0] / ((float)B_ROWS * (float)P_ROWS);
            out[1] = mean_pos;
            out[2] = mean_neg;
            out[3] = mean_pos - mean_neg;
        }
    }
}

extern "C" void kernel_launch(void* const* d_in, const int* in_sizes, int n_in,
                              void* d_out, int out_size, void* d_ws, size_t ws_size,
                              hipStream_t stream) {
    const float* anc = (const float*)d_in[0];
    const float* pos = (const float*)d_in[1];
    const float* neg = (const float*)d_in[2];
    float* out = (float*)d_out;

    fp8_t* a8 = (fp8_t*)d_ws;
    fp8_t* p8 = a8 + (size_t)B_ROWS * D_DIM;
    fp8_t* n8 = p8 + (size_t)P_ROWS * D_DIM;
    float* fsec = (float*)(n8 + (size_t)N_ROWS * D_DIM);  // 12MB offset, 64B-aligned
    float* S    = fsec;                        // 4096
    float* csA  = S + B_ROWS;                  // 512*16
    float* csP  = csA + D_DIM * CS_STRIDE;     // 512*16
    float* csN  = csP + D_DIM * CS_STRIDE;     // 512*16
    float* lsum = csN + D_DIM * CS_STRIDE;     // 1 (+3 pad)
    uint32* cnt = (uint32*)(lsum + 4);         // 4 barrier counters, 16B-aligned

    // ws is re-poisoned 0xAA before every launch -> zero accumulators + counters
    (void)hipMemsetAsync(fsec, 0, (B_ROWS + 3 * D_DIM * CS_STRIDE + 8) * sizeof(float), stream);

    fused_all<<<GRID, 512, 0, stream>>>(anc, pos, neg, a8, p8, n8,
                                        S, csA, csP, csN, lsum, cnt, out);
}

// Round 8
// 204.822 us; speedup vs baseline: 1.4547x; 1.4547x over previous
//
#include <hip/hip_runtime.h>
#include <hip/hip_bf16.h>

// InfoNCE: a[4096,512], p[4096,512], n[16384,512] f32 -> 4 f32 scalars.
// R12: split kernels again (stream order > grid barriers) + R11's proven
//     32x64 wave retile + finalize folded into gemm1 (last-block arrive).
//     R11 post-mortem: fused dispatch 240us with BOTH pipes idle (14%/14%),
//     traffic ~= split-sum -> stall source is the grid-barrier machinery
//     (512 per-block agent-scope threadfence = buffer_wbl2/inv L2 storms +
//     512 spinners on one line), not spills (VGPR 64 = af+acc data; acc in
//     AGPRs). Launches 5 -> 4: memset, norm, gemm0, gemm1+finalize.
// ws layout: a8(2MB) p8(2MB) n8(8MB) | S[4096] csA[8192] csP[8192] csN[8192]
//            lsum[1] pad[3] cnt[4]

#define D_DIM 512
#define B_ROWS 4096
#define P_ROWS 4096
#define N_ROWS 16384
#define INV_T 14.285714285714286f
#define EPS_L 1e-8f
#define CS_STRIDE 16
#define GRID 512

typedef unsigned char fp8_t;
typedef __attribute__((ext_vector_type(4))) float floatx4;   // MFMA C/D frag
typedef __attribute__((ext_vector_type(2))) long longx2;     // 16B = 2 MFMA operands
typedef unsigned int uint32;

#define BM 128
#define BN 128
#define BKB 64   // K-elements per B tile == bytes per row per tile (fp8)
#define NBUF 4

typedef const __attribute__((address_space(1))) unsigned int* as1_u32p;
typedef __attribute__((address_space(3))) unsigned int* as3_u32p;

__device__ __forceinline__ void load_lds16(const void* g, void* l) {
    // each lane writes 16B at (wave-uniform l) + lane*16
    __builtin_amdgcn_global_load_lds((as1_u32p)g, (as3_u32p)l, 16, 0, 0);
}

// ---- fused: L2-normalize rows -> fp8 e4m3, and accumulate fp32 column sums ----
// grid = 1024 blocks x 256 thr. Segments: b<256 -> A, b<512 -> P, else -> N.
__global__ __launch_bounds__(256) void norm_colsum(
        const float* __restrict__ a, const float* __restrict__ p, const float* __restrict__ n,
        fp8_t* __restrict__ a8, fp8_t* __restrict__ p8, fp8_t* __restrict__ n8,
        float* __restrict__ csA, float* __restrict__ csP, float* __restrict__ csN) {
    const float* in; fp8_t* outp; float* cs; int rows, nb, bseg;
    int b = blockIdx.x;
    if (b < 256)      { in = a; outp = a8; cs = csA; rows = B_ROWS; nb = 256; bseg = b; }
    else if (b < 512) { in = p; outp = p8; cs = csP; rows = P_ROWS; nb = 256; bseg = b - 256; }
    else              { in = n; outp = n8; cs = csN; rows = N_ROWS; nb = 512; bseg = b - 512; }

    const int wave = threadIdx.x >> 6;
    const int lane = threadIdx.x & 63;

    float cs0[4] = {0.f, 0.f, 0.f, 0.f};
    float cs1[4] = {0.f, 0.f, 0.f, 0.f};

    for (int chunk = bseg; chunk < (rows >> 2); chunk += nb) {
        int r = chunk * 4 + wave;
        const float4* rp = reinterpret_cast<const float4*>(in + (size_t)r * D_DIM);
        float4 v0 = rp[lane];
        float4 v1 = rp[lane + 64];
        float ss = v0.x*v0.x + v0.y*v0.y + v0.z*v0.z + v0.w*v0.w
                 + v1.x*v1.x + v1.y*v1.y + v1.z*v1.z + v1.w*v1.w;
#pragma unroll
        for (int off = 1; off < 64; off <<= 1) ss += __shfl_xor(ss, off);
        float inv = 1.0f / fmaxf(sqrtf(ss), 1e-12f);
        float f0x = v0.x*inv, f0y = v0.y*inv, f0z = v0.z*inv, f0w = v0.w*inv;
        float f1x = v1.x*inv, f1y = v1.y*inv, f1z = v1.z*inv, f1w = v1.w*inv;
        cs0[0] += f0x; cs0[1] += f0y; cs0[2] += f0z; cs0[3] += f0w;
        cs1[0] += f1x; cs1[1] += f1y; cs1[2] += f1z; cs1[3] += f1w;
        // pack 4 floats -> 4 fp8 e4m3 bytes (RNE hw cvt)
        int pk0 = __builtin_amdgcn_cvt_pk_fp8_f32(f0x, f0y, 0, 0);
        pk0     = __builtin_amdgcn_cvt_pk_fp8_f32(f0z, f0w, pk0, 1);
        int pk1 = __builtin_amdgcn_cvt_pk_fp8_f32(f1x, f1y, 0, 0);
        pk1     = __builtin_amdgcn_cvt_pk_fp8_f32(f1z, f1w, pk1, 1);
        uint32* op = reinterpret_cast<uint32*>(outp + (size_t)r * D_DIM);
        op[lane]      = (uint32)pk0;   // bytes 4*lane .. 4*lane+3
        op[lane + 64] = (uint32)pk1;   // bytes 256+4*lane ..
    }

    // block-level colsum reduce: LDS atomics (4-way max contention), then one
    // global atomic per column per block, spread across 64B lines.
    __shared__ float csh[D_DIM];
    if (threadIdx.x < 256) { csh[threadIdx.x] = 0.f; csh[threadIdx.x + 256] = 0.f; }
    __syncthreads();
#pragma unroll
    for (int j = 0; j < 4; ++j) {
        atomicAdd(&csh[lane * 4 + j], cs0[j]);
        atomicAdd(&csh[256 + lane * 4 + j], cs1[j]);
    }
    __syncthreads();
    if (threadIdx.x < 256) {
        atomicAdd(&cs[(size_t)threadIdx.x * CS_STRIDE], csh[threadIdx.x]);
        atomicAdd(&cs[(size_t)(threadIdx.x + 256) * CS_STRIDE], csh[threadIdx.x + 256]);
    }
}

// ---- gemm phase body: A in regs (32 rows/wave), B 4-ring LDS, 1 barrier/iter.
// Wave grid 4(M: wr) x 2(N: wc); per wave 32x64 output, 4 b128 B-reads/k-chunk.
// EPI==0: S[row] += sum_col exp(C*invT); EPI==1: lsum over -log(pe/(pe+S)+eps).
template <int EPI, int TN>
__device__ __forceinline__ void gemm_body(const fp8_t* __restrict__ A,
                                          const fp8_t* __restrict__ Bm,
                                          float* __restrict__ S,
                                          float* __restrict__ loss_sum,
                                          int m0, int nt0, int tid,
                                          fp8_t (*Bl)[BN * BKB], float* csh) {
    const int lane = tid & 63;
    const int w    = tid >> 6;      // 0..7
    const int wr   = w >> 1;        // 0..3: 32-row band
    const int wc   = w & 1;         // 0..1: 64-col half
    const int lr   = lane & 15;
    const int q    = lane >> 4;

    // A fragments: rows m0+wr*32+{lr,16+lr}, true bytes kt*64+q*16 (matches
    // B's granule mapping -> per-(q,half) true-k identical on both sides).
    longx2 af[2][8];
#pragma unroll
    for (int rt = 0; rt < 2; ++rt) {
        const fp8_t* arow = A + (size_t)(m0 + wr * 32 + rt * 16 + lr) * D_DIM + q * 16;
#pragma unroll
        for (int kt = 0; kt < 8; ++kt)
            af[rt][kt] = *reinterpret_cast<const longx2*>(arow + kt * 64);
    }

    // B staging (R7/R9's measured-zero-conflict scheme, stride 64):
    // LDS[r*64 + s*16] holds true granule s^((r>>1)&3) of row r.
    const int sr = lane >> 2;
    const int sg = (lane & 3) ^ ((lane >> 3) & 3);
    const fp8_t* bbase = Bm + (size_t)(nt0 * BN + w * 16 + sr) * D_DIM + sg * 16;
    const int goff = (q ^ ((lr >> 1) & 3)) << 4;

    auto stage = [&](int tt) {
        load_lds16(bbase + (size_t)(tt >> 3) * (size_t)(BN * D_DIM)
                         + (size_t)((tt & 7) * BKB),
                   &Bl[tt & 3][w * 16 * BKB]);
    };

    float vac[2][4];
    float Sv[2][4];
    float lsum = 0.f;
    if (EPI == 0) {
#pragma unroll
        for (int rt = 0; rt < 2; ++rt)
#pragma unroll
            for (int reg = 0; reg < 4; ++reg) vac[rt][reg] = 0.f;
    } else {
#pragma unroll
        for (int rt = 0; rt < 2; ++rt)
#pragma unroll
            for (int reg = 0; reg < 4; ++reg)
                Sv[rt][reg] = S[m0 + wr * 32 + rt * 16 + q * 4 + reg];
    }

    stage(0);
    stage(1);

    for (int j = 0; j < TN; ++j) {
        floatx4 acc[2][4];
#pragma unroll
        for (int rt = 0; rt < 2; ++rt)
#pragma unroll
            for (int ct = 0; ct < 4; ++ct) acc[rt][ct] = (floatx4){0.f, 0.f, 0.f, 0.f};

#pragma unroll
        for (int kt = 0; kt < 8; ++kt) {
            const int tt = j * 8 + kt;
            if (tt < TN * 8 - 2) {
                stage(tt + 2);   // ring dist 2, depth 4: writers never collide
                asm volatile("s_waitcnt vmcnt(2)" ::: "memory");  // tile tt landed
            } else if (tt == TN * 8 - 2) {
                asm volatile("s_waitcnt vmcnt(1)" ::: "memory");
            } else {
                asm volatile("s_waitcnt vmcnt(0)" ::: "memory");
            }
            __builtin_amdgcn_sched_barrier(0);
            __builtin_amdgcn_s_barrier();   // only barrier: tile tt resident
            __builtin_amdgcn_sched_barrier(0);

            const fp8_t* bl = &Bl[tt & 3][0];
            __builtin_amdgcn_s_setprio(1);
#pragma unroll
            for (int ct = 0; ct < 4; ++ct) {
                const int r = wc * 64 + ct * 16 + lr;
                longx2 bv = *reinterpret_cast<const longx2*>(&bl[r * BKB + goff]);
                acc[0][ct] = __builtin_amdgcn_mfma_f32_16x16x32_fp8_fp8(
                    af[0][kt].x, bv.x, acc[0][ct], 0, 0, 0);
                acc[1][ct] = __builtin_amdgcn_mfma_f32_16x16x32_fp8_fp8(
                    af[1][kt].x, bv.x, acc[1][ct], 0, 0, 0);
                acc[0][ct] = __builtin_amdgcn_mfma_f32_16x16x32_fp8_fp8(
                    af[0][kt].y, bv.y, acc[0][ct], 0, 0, 0);
                acc[1][ct] = __builtin_amdgcn_mfma_f32_16x16x32_fp8_fp8(
                    af[1][kt].y, bv.y, acc[1][ct], 0, 0, 0);
            }
            __builtin_amdgcn_s_setprio(0);
            __builtin_amdgcn_sched_barrier(0);
        }

        // per-n-tile epilogue, register-only (vmcnt counts stay exact).
        // C/D layout: col = lane&15, row = (lane>>4)*4 + reg
        if (EPI == 0) {
#pragma unroll
            for (int rt = 0; rt < 2; ++rt)
#pragma unroll
                for (int reg = 0; reg < 4; ++reg) {
                    float v = 0.f;
#pragma unroll
                    for (int ct = 0; ct < 4; ++ct) v += __expf(acc[rt][ct][reg] * INV_T);
                    vac[rt][reg] += v;
                }
        } else {
#pragma unroll
            for (int rt = 0; rt < 2; ++rt)
#pragma unroll
                for (int reg = 0; reg < 4; ++reg) {
                    float s = Sv[rt][reg];
#pragma unroll
                    for (int ct = 0; ct < 4; ++ct) {
                        float pe = __expf(acc[rt][ct][reg] * INV_T);
                        lsum -= __logf(pe / (pe + s) + EPS_L);
                    }
                }
        }
    }

    if (EPI == 0) {
#pragma unroll
        for (int rt = 0; rt < 2; ++rt)
#pragma unroll
            for (int reg = 0; reg < 4; ++reg) {
                float v = vac[rt][reg];
                v += __shfl_xor(v, 1);
                v += __shfl_xor(v, 2);
                v += __shfl_xor(v, 4);
                v += __shfl_xor(v, 8);
                if (lr == 0)
                    atomicAdd(&S[m0 + wr * 32 + rt * 16 + q * 4 + reg], v);
            }
    } else {
#pragma unroll
        for (int off = 1; off < 64; off <<= 1) lsum += __shfl_xor(lsum, off);
        __syncthreads();
        if (lane == 0) csh[w] = lsum;
        __syncthreads();
        if (tid == 0) {
            float s = 0.f;
#pragma unroll
            for (int i = 0; i < 8; ++i) s += csh[i];
            atomicAdd(loss_sum, s);
        }
    }
}

// ---- gemm0: neg pass ----
__global__ __launch_bounds__(512, 4) void gemm_neg(const fp8_t* __restrict__ A,
                                                   const fp8_t* __restrict__ Bm,
                                                   float* __restrict__ S) {
    __shared__ fp8_t Bl[NBUF][BN * BKB];   // 32 KB ring
    __shared__ float csh[32];
    gemm_body<0, 8>(A, Bm, S, nullptr, blockIdx.y * BM, blockIdx.x * 8,
                    (int)threadIdx.x, Bl, csh);
}

// ---- gemm1 + finalize (last-block arrive) ----
__global__ __launch_bounds__(512, 4) void gemm_pos_fin(
        const fp8_t* __restrict__ A, const fp8_t* __restrict__ Bm,
        float* __restrict__ S, float* __restrict__ lsum,
        const float* __restrict__ csA, const float* __restrict__ csP,
        const float* __restrict__ csN, uint32* __restrict__ cnt,
        float* __restrict__ out) {
    __shared__ fp8_t Bl[NBUF][BN * BKB];
    __shared__ float csh[32];
    __shared__ int lastf;

    const int tid  = threadIdx.x;
    const int lane = tid & 63;
    const int w    = tid >> 6;

    gemm_body<1, 2>(A, Bm, S, lsum, blockIdx.y * BM, blockIdx.x * 2, tid, Bl, csh);

    __syncthreads();
    if (tid == 0) {
        __threadfence();
        uint32 p = atomicAdd(cnt, 1u);
        lastf = (p == GRID - 1);
    }
    __syncthreads();
    if (lastf) {
        __threadfence();
        float av = csA[(size_t)tid * CS_STRIDE];
        float dp = av * csP[(size_t)tid * CS_STRIDE];
        float dn = av * csN[(size_t)tid * CS_STRIDE];
#pragma unroll
        for (int off = 1; off < 64; off <<= 1) {
            dp += __shfl_xor(dp, off);
            dn += __shfl_xor(dn, off);
        }
        float* red = csh;
        __syncthreads();
        if (lane == 0) { red[w] = dp; red[8 + w] = dn; }
        __syncthreads();
        if (tid == 0) {
            float sdp = 0.f, sdn = 0.f;
#pragma unroll
            for (int i = 0; i < 8; ++i) { sdp += red[i]; sdn += red[8 + i]; }
            float mean_pos = sdp * INV_T / ((float)B_ROWS * (float)P_ROWS);
            float mean_neg = sdn * INV_T / ((float)B_ROWS * (float)N_ROWS);
            out[0] = lsum[0] / ((float)B_ROWS * (float)P_ROWS);
            out[1] = mean_pos;
            out[2] = mean_neg;
            out[3] = mean_pos - mean_neg;
        }
    }
}

extern "C" void kernel_launch(void* const* d_in, const int* in_sizes, int n_in,
                              void* d_out, int out_size, void* d_ws, size_t ws_size,
                              hipStream_t stream) {
    const float* anc = (const float*)d_in[0];
    const float* pos = (const float*)d_in[1];
    const float* neg = (const float*)d_in[2];
    float* out = (float*)d_out;

    fp8_t* a8 = (fp8_t*)d_ws;
    fp8_t* p8 = a8 + (size_t)B_ROWS * D_DIM;
    fp8_t* n8 = p8 + (size_t)P_ROWS * D_DIM;
    float* fsec = (float*)(n8 + (size_t)N_ROWS * D_DIM);  // 12MB offset, 64B-aligned
    float* S    = fsec;                        // 4096
    float* csA  = S + B_ROWS;                  // 512*16
    float* csP  = csA + D_DIM * CS_STRIDE;     // 512*16
    float* csN  = csP + D_DIM * CS_STRIDE;     // 512*16
    float* lsum = csN + D_DIM * CS_STRIDE;     // 1 (+3 pad)
    uint32* cnt = (uint32*)(lsum + 4);         // arrive counter

    // ws is re-poisoned 0xAA before every launch -> zero accumulators + counter
    (void)hipMemsetAsync(fsec, 0, (B_ROWS + 3 * D_DIM * CS_STRIDE + 8) * sizeof(float), stream);

    norm_colsum<<<1024, 256, 0, stream>>>(anc, pos, neg, a8, p8, n8, csA, csP, csN);

    gemm_neg<<<dim3((N_ROWS / BN) / 8, B_ROWS / BM), 512, 0, stream>>>(a8, n8, S);
    gemm_pos_fin<<<dim3((P_ROWS / BN) / 2, B_ROWS / BM), 512, 0, stream>>>(
        a8, p8, S, lsum, csA, csP, csN, cnt, out);
}